// Round 15
// baseline (212.684 us; speedup 1.0000x reference)
//
#include <hip/hip_runtime.h>
#include <hip/hip_bf16.h>

// Problem constants
#define Bb 2
#define Nn 4096
#define Cc 1024
#define Hh 16
#define Dd 64
#define Mm (Bb*Nn)      // 8192
#define W2 10
#define WINSZ 21        // 2*W2+1

typedef __attribute__((ext_vector_type(8))) short  bf16x8s;
typedef __attribute__((ext_vector_type(4))) float  f32x4;
typedef __attribute__((ext_vector_type(4))) unsigned short us4;

#define AS1 __attribute__((address_space(1)))
#define AS3 __attribute__((address_space(3)))

__device__ __forceinline__ unsigned short f2bf(float f) {
  unsigned int u = __float_as_uint(f);
  u += 0x7FFFu + ((u >> 16) & 1u);
  return (unsigned short)(u >> 16);
}
__device__ __forceinline__ float bflo(unsigned int u) { return __uint_as_float(u << 16); }
__device__ __forceinline__ float bfhi(unsigned int u) { return __uint_as_float(u & 0xFFFF0000u); }

__device__ __forceinline__ us4 cvt4(float4 v) {
  us4 o;
  o.x = f2bf(v.x); o.y = f2bf(v.y); o.z = f2bf(v.z); o.w = f2bf(v.w);
  return o;
}

// ---------------- fused fp32->bf16 converts + bias gather (one launch) ----------------
__global__ __launch_bounds__(256) void cvt_all(const float4* __restrict__ q,
                                               const float4* __restrict__ wq,
                                               const float4* __restrict__ wk,
                                               const float4* __restrict__ wv,
                                               const float4* __restrict__ wo,
                                               const float* __restrict__ bq,
                                               const float* __restrict__ bk,
                                               const float* __restrict__ bv,
                                               us4* __restrict__ qb4,
                                               us4* __restrict__ wqkv4,
                                               us4* __restrict__ wo4,
                                               float* __restrict__ bqkv) {
  const int NQ = 2097152, NW = 262144, TOT = NQ + 4 * NW;
  const int gid = blockIdx.x * 256 + threadIdx.x;
  const int stride = gridDim.x * 256;
  for (int i = gid; i < TOT; i += stride) {
    if (i < NQ) {
      qb4[i] = cvt4(q[i]);
    } else {
      int j = i - NQ;
      int r = j >> 18, k = j & (NW - 1);
      if (r == 0)      wqkv4[k]          = cvt4(wq[k]);
      else if (r == 1) wqkv4[NW + k]     = cvt4(wk[k]);
      else if (r == 2) wqkv4[2 * NW + k] = cvt4(wv[k]);
      else             wo4[k]            = cvt4(wo[k]);
    }
  }
  if (gid < 3072) {
    float v = (gid < 1024) ? bq[gid] : (gid < 2048) ? bk[gid - 1024] : bv[gid - 2048];
    bqkv[gid] = v;
  }
}

// ---------------- 128x256 GEMM, B direct global->reg (K=1024) ----------------
// C[m,n] = sum_k A[m,k]*B[n,k] + bias[n]. 8 waves (2M x 4N, per-wave 64x64).
// A: LDS, 3x16KB buffers, flight-2 (R7-proven ledger), chunk-XOR swizzle.
// B: NO LDS — per-wave fragments loaded global->reg (L2-resident weights),
//    prefetched one K-tile ahead; correctness via compiler reg-dependency waits.
// End-of-tile manual wait vmcnt(10): allows B(t+1)[8]+A(t+2)[2] in flight and
// guarantees A(t+1) landed (>=10 vector-ops issued after it in any interleave).
template<bool OUT_BF16>
__global__ __launch_bounds__(512) void gemm_bd(const unsigned short* __restrict__ A,
                                               const unsigned short* __restrict__ Bm,
                                               const float* __restrict__ bias,
                                               void* __restrict__ Cout,
                                               int N) {
  constexpr int K = 1024, NT = 16;
  __shared__ unsigned short lds[3][8192];   // 3 x 16KB A buffers = 48 KB

  const int tid = threadIdx.x, wid = tid >> 6, lane = tid & 63;
  const int wm = wid >> 2, wn = wid & 3;

  // bijective XCD swizzle + column-major tile walk (weight panel dwells in L2)
  const int nwg = gridDim.x, cpx = nwg >> 3, bid = blockIdx.x;
  const int swz = (bid & 7) * cpx + (bid >> 3);
  constexpr int NBM = Mm / 128;   // 64
  const int m0 = (swz % NBM) << 7, n0 = (swz / NBM) << 8;

  // A staging: 2 instrs/tile; lane -> row wid*8+(lane>>3), slot lane&7;
  // pre-swizzled global chunk = (lane&7)^(lane>>3)
  const int rbase = wid * 8 + (lane >> 3);
  const int cst = ((lane & 7) ^ (lane >> 3)) * 8;
  const unsigned short* aS0 = A + (size_t)(m0 + rbase) * K + cst;
  const unsigned short* aS1 = A + (size_t)(m0 + 64 + rbase) * K + cst;
  const int dA0 = wid * 512, dA1 = 4096 + wid * 512;

  // B direct: per-lane fragment base. frag(kk,fn) at fn*16*K + t*64 + kk*32.
  const unsigned short* bBase = Bm + (size_t)(n0 + wn * 64 + (lane & 15)) * K + (lane >> 4) * 8;

#define STGA(bf, kt) do { const size_t ko = (size_t)(kt) * 64;                              \
    __builtin_amdgcn_global_load_lds((AS1 const void*)(aS0 + ko), (AS3 void*)(&lds[bf][dA0]), 16, 0, 0); \
    __builtin_amdgcn_global_load_lds((AS1 const void*)(aS1 + ko), (AS3 void*)(&lds[bf][dA1]), 16, 0, 0); \
  } while (0)

#define BLOAD(dst, kt) do { _Pragma("unroll") for (int i = 0; i < 8; ++i)                   \
    dst[i] = *(const bf16x8s*)(bBase + (size_t)(i & 3) * 16 * K + (size_t)(kt) * 64 + (i >> 2) * 32); \
  } while (0)

  // A-frag LDS offsets: row = wm*64 + f*16 + (lane&15); row&7 == lane&7.
  int aoff[2][4];
#pragma unroll
  for (int kk = 0; kk < 2; ++kk) {
    const int chs = ((kk * 4 + (lane >> 4)) ^ (lane & 7)) * 8;
#pragma unroll
    for (int f = 0; f < 4; ++f)
      aoff[kk][f] = (wm * 64 + f * 16 + (lane & 15)) * 64 + chs;
  }

  f32x4 acc[4][4] = {};
  bf16x8s b0[8], b1[8];

  STGA(0, 0);
  STGA(1, 1);
  BLOAD(b0, 0);
  asm volatile("s_waitcnt vmcnt(10)" ::: "memory");   // A(0) landed; A(1)+B(0) may fly
  __builtin_amdgcn_sched_barrier(0);
  __builtin_amdgcn_s_barrier();
  __builtin_amdgcn_sched_barrier(0);

  int cur = 0, stg = 2;
#pragma unroll 2
  for (int t = 0; t < NT; ++t) {
    bf16x8s (&bc)[8] = (t & 1) ? b1 : b0;   // static under unroll-2 (rule #20)
    bf16x8s (&bn)[8] = (t & 1) ? b0 : b1;

    if (t + 2 < NT) STGA(stg, t + 2);   // buf freed at end-of-tile-(t-1) barrier
    if (t + 1 < NT) BLOAD(bn, t + 1);   // compiler-managed reg dependency

    const unsigned short* L = &lds[cur][0];
    bf16x8s a[2][4];
#pragma unroll
    for (int kk = 0; kk < 2; ++kk)
#pragma unroll
      for (int f = 0; f < 4; ++f)
        a[kk][f] = *(const bf16x8s*)(L + aoff[kk][f]);

    __builtin_amdgcn_s_setprio(1);
#pragma unroll
    for (int kk = 0; kk < 2; ++kk)
#pragma unroll
      for (int fm = 0; fm < 4; ++fm)
#pragma unroll
        for (int fn = 0; fn < 4; ++fn)
          acc[fm][fn] = __builtin_amdgcn_mfma_f32_16x16x32_bf16(a[kk][fm], bc[kk * 4 + fn], acc[fm][fn], 0, 0, 0);
    __builtin_amdgcn_s_setprio(0);

    if (t + 1 < NT) {
      if (t + 2 < NT) asm volatile("s_waitcnt vmcnt(10)" ::: "memory");  // A(t+1) certain
      else            asm volatile("s_waitcnt vmcnt(8)"  ::: "memory");  // tail: only B(t+1) newest
      __builtin_amdgcn_sched_barrier(0);
      __builtin_amdgcn_s_barrier();
      __builtin_amdgcn_sched_barrier(0);
    }
    cur = (cur == 2) ? 0 : cur + 1;
    stg = (stg == 2) ? 0 : stg + 1;
  }
#undef STGA
#undef BLOAD

  // epilogue: C/D layout col=lane&15, row=(lane>>4)*4+r
  const int r0 = m0 + wm * 64 + (lane >> 4) * 4;
  const int c0 = n0 + wn * 64 + (lane & 15);
#pragma unroll
  for (int fm = 0; fm < 4; ++fm) {
#pragma unroll
    for (int fn = 0; fn < 4; ++fn) {
      const int col = c0 + fn * 16;
      const float bv = bias[col];
#pragma unroll
      for (int r = 0; r < 4; ++r) {
        const int row = r0 + fm * 16 + r;
        const float v = acc[fm][fn][r] + bv;
        if (OUT_BF16)
          ((unsigned short*)Cout)[(size_t)row * N + col] = f2bf(v);
        else
          ((float*)Cout)[(size_t)row * N + col] = v;
      }
    }
  }
}

// ---------------- banded local attention: 2 threads per (b,h,n) row ----------------
#define TN 128
#define KVROWS (TN + 2 * W2)   // 148 staged rows

__global__ void attn_kernel(const unsigned short* __restrict__ QKV, // [Mm][3072]
                            unsigned short* __restrict__ AO,        // [Mm][1024]
                            float* __restrict__ attn_last) {        // [Bb*Hh*11]
  __shared__ uint4 Kl[KVROWS * 8];
  __shared__ uint4 Vl[KVROWS * 8];

  const int nt = Nn / TN;            // 32
  const int bid = blockIdx.x;
  const int tile = bid & (nt - 1);
  const int bh = bid / nt;
  const int h = bh & (Hh - 1), b = bh / Hh;
  const int n0 = tile * TN;
  const int tid = threadIdx.x;

  for (int idx = tid; idx < KVROWS * 8; idx += 256) {
    const int r = idx >> 3, c = idx & 7;
    const int pos = n0 - W2 + r;
    uint4 kv = make_uint4(0, 0, 0, 0), vv = make_uint4(0, 0, 0, 0);
    if (pos >= 0 && pos < Nn) {
      const uint4* row = (const uint4*)(QKV + (size_t)(b * Nn + pos) * 3072);
      kv = row[128 + h * 8 + c];
      vv = row[256 + h * 8 + c];
    }
    const int slot = c ^ (r & 7);
    Kl[r * 8 + slot] = kv;
    Vl[r * 8 + slot] = vv;
  }
  __syncthreads();

  const int row  = tid >> 1;
  const int half = tid & 1;
  const int n = n0 + row;
  const size_t m = (size_t)b * Nn + n;

  const uint4* qrow = (const uint4*)(QKV + m * 3072) + h * 8 + half * 4;
  const uint4 qd0 = qrow[0], qd1 = qrow[1], qd2 = qrow[2], qd3 = qrow[3];

  float p[WINSZ];
#pragma unroll
  for (int w = 0; w < WINSZ; ++w) p[w] = 0.f;

#pragma unroll
  for (int c = 0; c < 4; ++c) {
    const uint4 qv = (c == 0) ? qd0 : (c == 1) ? qd1 : (c == 2) ? qd2 : qd3;
    const float q0 = bflo(qv.x), q1 = bfhi(qv.x);
    const float q2 = bflo(qv.y), q3 = bfhi(qv.y);
    const float q4 = bflo(qv.z), q5 = bfhi(qv.z);
    const float q6 = bflo(qv.w), q7 = bfhi(qv.w);
#pragma unroll 7
    for (int w = 0; w < WINSZ; ++w) {
      const int r = row + w;
      const uint4 v = Kl[r * 8 + ((half * 4 + c) ^ (r & 7))];
      float a0 = q0 * bflo(v.x);
      float a1 = q1 * bfhi(v.x);
      a0 += q2 * bflo(v.y);
      a1 += q3 * bfhi(v.y);
      a0 += q4 * bflo(v.z);
      a1 += q5 * bfhi(v.z);
      a0 += q6 * bflo(v.w);
      a1 += q7 * bfhi(v.w);
      p[w] += a0 + a1;
    }
  }

#pragma unroll
  for (int w = 0; w < WINSZ; ++w) {
    float t = p[w];
    t += __shfl_xor(t, 1, 64);
    const int pos = n - W2 + w;
    p[w] = (pos < 0 || pos >= Nn) ? -1e30f : t * 0.125f;
  }
  float mx = p[0];
#pragma unroll
  for (int w = 1; w < WINSZ; ++w) mx = fmaxf(mx, p[w]);
  float sum = 0.f;
#pragma unroll
  for (int w = 0; w < WINSZ; ++w) { p[w] = __expf(p[w] - mx); sum += p[w]; }
  const float inv = 1.0f / sum;

  if (n == Nn - 1 && half == 0) {
#pragma unroll
    for (int w = 0; w <= W2; ++w)
      attn_last[(b * Hh + h) * (W2 + 1) + w] = p[w] * inv;
  }

  uint4* orow = (uint4*)(AO + m * Cc + h * Dd) + half * 4;
#pragma unroll
  for (int c = 0; c < 4; ++c) {
    float o0 = 0.f, o1 = 0.f, o2 = 0.f, o3 = 0.f;
    float o4 = 0.f, o5 = 0.f, o6 = 0.f, o7 = 0.f;
#pragma unroll 7
    for (int w = 0; w < WINSZ; ++w) {
      const int r = row + w;
      const uint4 v = Vl[r * 8 + ((half * 4 + c) ^ (r & 7))];
      const float pw = p[w];
      o0 += pw * bflo(v.x);
      o1 += pw * bfhi(v.x);
      o2 += pw * bflo(v.y);
      o3 += pw * bfhi(v.y);
      o4 += pw * bflo(v.z);
      o5 += pw * bfhi(v.z);
      o6 += pw * bflo(v.w);
      o7 += pw * bfhi(v.w);
    }
    unsigned int d0 = (unsigned int)f2bf(o0 * inv) | ((unsigned int)f2bf(o1 * inv) << 16);
    unsigned int d1 = (unsigned int)f2bf(o2 * inv) | ((unsigned int)f2bf(o3 * inv) << 16);
    unsigned int d2 = (unsigned int)f2bf(o4 * inv) | ((unsigned int)f2bf(o5 * inv) << 16);
    unsigned int d3 = (unsigned int)f2bf(o6 * inv) | ((unsigned int)f2bf(o7 * inv) << 16);
    orow[c] = make_uint4(d0, d1, d2, d3);
  }
}

// ---------------- launch ----------------
extern "C" void kernel_launch(void* const* d_in, const int* in_sizes, int n_in,
                              void* d_out, int out_size, void* d_ws, size_t ws_size,
                              hipStream_t stream) {
  const float* q    = (const float*)d_in[0];
  const float* Wq_w = (const float*)d_in[1];
  const float* Wq_b = (const float*)d_in[2];
  const float* Wk_w = (const float*)d_in[3];
  const float* Wk_b = (const float*)d_in[4];
  const float* Wv_w = (const float*)d_in[5];
  const float* Wv_b = (const float*)d_in[6];
  const float* Wo_w = (const float*)d_in[7];
  const float* Wo_b = (const float*)d_in[8];
  float* out = (float*)d_out;                       // [Mm*Cc] + [Bb*Hh*11]
  float* attn_last = out + (size_t)Mm * Cc;

  // workspace carve (bytes)
  char* ws = (char*)d_ws;
  unsigned short* qb   = (unsigned short*)(ws);                       // 16 MB
  unsigned short* Wqkv = (unsigned short*)(ws + 16777216);            // 6 MB
  unsigned short* Wo16 = (unsigned short*)(ws + 16777216 + 6291456);  // 2 MB
  float*          bqkv = (float*)(ws + 25165824);                     // 3072 f32
  unsigned short* QKV  = (unsigned short*)(ws + 25182208);            // 48 MB
  unsigned short* AO   = (unsigned short*)(ws + 75513856);            // 16 MB

  // 1) fused converts (q, Wq, Wk, Wv, Wo) + bias gather — one launch
  cvt_all<<<2048, 256, 0, stream>>>((const float4*)q,
                                    (const float4*)Wq_w, (const float4*)Wk_w,
                                    (const float4*)Wv_w, (const float4*)Wo_w,
                                    Wq_b, Wk_b, Wv_b,
                                    (us4*)qb, (us4*)Wqkv, (us4*)Wo16, bqkv);

  // 2) fused QKV projection: [8192,1024] x [3072,1024]^T -> bf16 [8192,3072]
  {
    dim3 grid((Mm / 128) * (3072 / 256));   // 768, %8==0
    gemm_bd<true><<<grid, 512, 0, stream>>>(qb, Wqkv, bqkv, (void*)QKV, 3072);
  }

  // 3) windowed attention -> bf16 [8192,1024] + attn_last tail of d_out
  {
    dim3 grid(Bb * Hh * (Nn / TN));
    attn_kernel<<<grid, 256, 0, stream>>>(QKV, AO, attn_last);
  }

  // 4) output projection: [8192,1024] x [1024,1024]^T -> fp32 d_out
  {
    dim3 grid((Mm / 128) * (Cc / 256));     // 256, %8==0
    gemm_bd<false><<<grid, 512, 0, stream>>>(AO, Wo16, Wo_b, (void*)out, Cc);
  }
}

// Round 16
// 147.253 us; speedup vs baseline: 1.4443x; 1.4443x over previous
//
#include <hip/hip_runtime.h>
#include <hip/hip_bf16.h>

// Problem constants
#define Bb 2
#define Nn 4096
#define Cc 1024
#define Hh 16
#define Dd 64
#define Mm (Bb*Nn)      // 8192
#define W2 10
#define WINSZ 21        // 2*W2+1

typedef __attribute__((ext_vector_type(8))) short  bf16x8s;
typedef __attribute__((ext_vector_type(4))) float  f32x4;
typedef __attribute__((ext_vector_type(4))) unsigned short us4;

#define AS1 __attribute__((address_space(1)))
#define AS3 __attribute__((address_space(3)))

__device__ __forceinline__ unsigned short f2bf(float f) {
  unsigned int u = __float_as_uint(f);
  u += 0x7FFFu + ((u >> 16) & 1u);
  return (unsigned short)(u >> 16);
}
__device__ __forceinline__ float bflo(unsigned int u) { return __uint_as_float(u << 16); }
__device__ __forceinline__ float bfhi(unsigned int u) { return __uint_as_float(u & 0xFFFF0000u); }

__device__ __forceinline__ us4 cvt4(float4 v) {
  us4 o;
  o.x = f2bf(v.x); o.y = f2bf(v.y); o.z = f2bf(v.z); o.w = f2bf(v.w);
  return o;
}

// ---------------- fused fp32->bf16 converts + bias gather (one launch) ----------------
__global__ __launch_bounds__(256) void cvt_all(const float4* __restrict__ q,
                                               const float4* __restrict__ wq,
                                               const float4* __restrict__ wk,
                                               const float4* __restrict__ wv,
                                               const float4* __restrict__ wo,
                                               const float* __restrict__ bq,
                                               const float* __restrict__ bk,
                                               const float* __restrict__ bv,
                                               us4* __restrict__ qb4,
                                               us4* __restrict__ wqkv4,
                                               us4* __restrict__ wo4,
                                               float* __restrict__ bqkv) {
  const int NQ = 2097152, NW = 262144, TOT = NQ + 4 * NW;
  const int gid = blockIdx.x * 256 + threadIdx.x;
  const int stride = gridDim.x * 256;
  for (int i = gid; i < TOT; i += stride) {
    if (i < NQ) {
      qb4[i] = cvt4(q[i]);
    } else {
      int j = i - NQ;
      int r = j >> 18, k = j & (NW - 1);
      if (r == 0)      wqkv4[k]          = cvt4(wq[k]);
      else if (r == 1) wqkv4[NW + k]     = cvt4(wk[k]);
      else if (r == 2) wqkv4[2 * NW + k] = cvt4(wv[k]);
      else             wo4[k]            = cvt4(wo[k]);
    }
  }
  if (gid < 3072) {
    float v = (gid < 1024) ? bq[gid] : (gid < 2048) ? bk[gid - 1024] : bv[gid - 2048];
    bqkv[gid] = v;
  }
}

// ---------------- 128x128 BK=64 flight-1 GEMM, 2 blocks/CU (K=1024) ----------------
// C[m,n] = sum_k A[m,k]*B[n,k] + bias[n]. 4 waves (2M x 2N, per-wave 64x64).
// TWO 32KB LDS buffers (64KB total -> 2 blocks/CU: m114 cross-block overlap hides
// the per-tile vmcnt(0)+barrier drain). R8-proven flight-1 ledger: STG(t+1)->buf^1
// at tile-top (buf^1's readers drained before previous barrier), ONE vmcnt(0)+
// s_barrier per tile. R7-proven chunk-XOR swizzle (0 conflicts): write side
// pre-swizzles GLOBAL chunk (lane&7)^(lane>>3); read slot = chunk ^ (row&7).
template<bool OUT_BF16>
__global__ __launch_bounds__(256) void gemm_22(const unsigned short* __restrict__ A,
                                               const unsigned short* __restrict__ Bm,
                                               const float* __restrict__ bias,
                                               void* __restrict__ Cout,
                                               int N) {
  constexpr int K = 1024, NT = 16;
  // per buffer: A[128][64] (8192 elems, 16KB) + B[128][64] = 16384 elems = 32 KB
  __shared__ unsigned short lds[2][16384];   // 64 KB

  const int tid = threadIdx.x, wid = tid >> 6, lane = tid & 63;
  const int wm = wid >> 1, wn = wid & 1;

  // bijective XCD swizzle + column-major tile walk (weight panel dwells in L2)
  const int nwg = gridDim.x, cpx = nwg >> 3, bid = blockIdx.x;
  const int swz = (bid & 7) * cpx + (bid >> 3);
  constexpr int NBM = Mm / 128;   // 64
  const int m0 = (swz % NBM) << 7, n0 = (swz / NBM) << 7;

  // staging: per wave 4 instrs for A (rows 32w..32w+31, 8 rows/instr) + 4 for B.
  // lane l -> row (l>>3), slot l&7; pre-swizzled global chunk = (l&7)^(l>>3).
  const int srow = lane >> 3;
  const int cst = ((lane & 7) ^ (lane >> 3)) * 8;
  const unsigned short* aS[4];
  const unsigned short* bS[4];
#pragma unroll
  for (int j = 0; j < 4; ++j) {
    aS[j] = A  + (size_t)(m0 + wid * 32 + j * 8 + srow) * K + cst;
    bS[j] = Bm + (size_t)(n0 + wid * 32 + j * 8 + srow) * K + cst;
  }
  const int dA = wid * 2048;          // elems; instr j at +512j
  const int dB = 8192 + wid * 2048;

#define STG(bf, kt) do {                                                                     \
    const size_t ko = (size_t)(kt) * 64;                                                     \
    __builtin_amdgcn_global_load_lds((AS1 const void*)(aS[0] + ko), (AS3 void*)(&lds[bf][dA       ]), 16, 0, 0); \
    __builtin_amdgcn_global_load_lds((AS1 const void*)(aS[1] + ko), (AS3 void*)(&lds[bf][dA +  512]), 16, 0, 0); \
    __builtin_amdgcn_global_load_lds((AS1 const void*)(aS[2] + ko), (AS3 void*)(&lds[bf][dA + 1024]), 16, 0, 0); \
    __builtin_amdgcn_global_load_lds((AS1 const void*)(aS[3] + ko), (AS3 void*)(&lds[bf][dA + 1536]), 16, 0, 0); \
    __builtin_amdgcn_global_load_lds((AS1 const void*)(bS[0] + ko), (AS3 void*)(&lds[bf][dB       ]), 16, 0, 0); \
    __builtin_amdgcn_global_load_lds((AS1 const void*)(bS[1] + ko), (AS3 void*)(&lds[bf][dB +  512]), 16, 0, 0); \
    __builtin_amdgcn_global_load_lds((AS1 const void*)(bS[2] + ko), (AS3 void*)(&lds[bf][dB + 1024]), 16, 0, 0); \
    __builtin_amdgcn_global_load_lds((AS1 const void*)(bS[3] + ko), (AS3 void*)(&lds[bf][dB + 1536]), 16, 0, 0); \
  } while (0)

  // fragment reads: row = wm*64 + f*16 + (lane&15); row&7 == lane&7.
  // chunk = kk*4 + (lane>>4); slot = chunk ^ (lane&7).
  int aoff[2][4], boff[2][4];
#pragma unroll
  for (int kk = 0; kk < 2; ++kk) {
    const int chs = ((kk * 4 + (lane >> 4)) ^ (lane & 7)) * 8;
#pragma unroll
    for (int f = 0; f < 4; ++f) {
      aoff[kk][f] = (wm * 64 + f * 16 + (lane & 15)) * 64 + chs;
      boff[kk][f] = 8192 + (wn * 64 + f * 16 + (lane & 15)) * 64 + chs;
    }
  }

  f32x4 acc[4][4] = {};

  STG(0, 0);
  asm volatile("s_waitcnt vmcnt(0)" ::: "memory");
  __builtin_amdgcn_sched_barrier(0);
  __builtin_amdgcn_s_barrier();
  __builtin_amdgcn_sched_barrier(0);

  int cur = 0;
#pragma unroll 1
  for (int t = 0; t < NT; ++t) {
    if (t + 1 < NT) STG(cur ^ 1, t + 1);   // buf^1's readers drained before prev barrier

    const unsigned short* L = &lds[cur][0];
    bf16x8s a[2][4], b[2][4];
#pragma unroll
    for (int kk = 0; kk < 2; ++kk)
#pragma unroll
      for (int f = 0; f < 4; ++f) {
        a[kk][f] = *(const bf16x8s*)(L + aoff[kk][f]);
        b[kk][f] = *(const bf16x8s*)(L + boff[kk][f]);
      }

    __builtin_amdgcn_s_setprio(1);
#pragma unroll
    for (int kk = 0; kk < 2; ++kk)
#pragma unroll
      for (int fm = 0; fm < 4; ++fm)
#pragma unroll
        for (int fn = 0; fn < 4; ++fn)
          acc[fm][fn] = __builtin_amdgcn_mfma_f32_16x16x32_bf16(a[kk][fm], b[kk][fn], acc[fm][fn], 0, 0, 0);
    __builtin_amdgcn_s_setprio(0);

    if (t + 1 < NT) {
      asm volatile("s_waitcnt vmcnt(0)" ::: "memory");   // t+1's 8 loads landed
      __builtin_amdgcn_sched_barrier(0);
      __builtin_amdgcn_s_barrier();
      __builtin_amdgcn_sched_barrier(0);
    }
    cur ^= 1;
  }
#undef STG

  // epilogue: C/D layout col=lane&15, row=(lane>>4)*4+r
  const int r0 = m0 + wm * 64 + (lane >> 4) * 4;
  const int c0 = n0 + wn * 64 + (lane & 15);
#pragma unroll
  for (int fm = 0; fm < 4; ++fm) {
#pragma unroll
    for (int fn = 0; fn < 4; ++fn) {
      const int col = c0 + fn * 16;
      const float bv = bias[col];
#pragma unroll
      for (int r = 0; r < 4; ++r) {
        const int row = r0 + fm * 16 + r;
        const float v = acc[fm][fn][r] + bv;
        if (OUT_BF16)
          ((unsigned short*)Cout)[(size_t)row * N + col] = f2bf(v);
        else
          ((float*)Cout)[(size_t)row * N + col] = v;
      }
    }
  }
}

// ---------------- banded local attention: 2 threads per (b,h,n) row ----------------
#define TN 128
#define KVROWS (TN + 2 * W2)   // 148 staged rows

__global__ void attn_kernel(const unsigned short* __restrict__ QKV, // [Mm][3072]
                            unsigned short* __restrict__ AO,        // [Mm][1024]
                            float* __restrict__ attn_last) {        // [Bb*Hh*11]
  __shared__ uint4 Kl[KVROWS * 8];
  __shared__ uint4 Vl[KVROWS * 8];

  const int nt = Nn / TN;            // 32
  const int bid = blockIdx.x;
  const int tile = bid & (nt - 1);
  const int bh = bid / nt;
  const int h = bh & (Hh - 1), b = bh / Hh;
  const int n0 = tile * TN;
  const int tid = threadIdx.x;

  for (int idx = tid; idx < KVROWS * 8; idx += 256) {
    const int r = idx >> 3, c = idx & 7;
    const int pos = n0 - W2 + r;
    uint4 kv = make_uint4(0, 0, 0, 0), vv = make_uint4(0, 0, 0, 0);
    if (pos >= 0 && pos < Nn) {
      const uint4* row = (const uint4*)(QKV + (size_t)(b * Nn + pos) * 3072);
      kv = row[128 + h * 8 + c];
      vv = row[256 + h * 8 + c];
    }
    const int slot = c ^ (r & 7);
    Kl[r * 8 + slot] = kv;
    Vl[r * 8 + slot] = vv;
  }
  __syncthreads();

  const int row  = tid >> 1;
  const int half = tid & 1;
  const int n = n0 + row;
  const size_t m = (size_t)b * Nn + n;

  const uint4* qrow = (const uint4*)(QKV + m * 3072) + h * 8 + half * 4;
  const uint4 qd0 = qrow[0], qd1 = qrow[1], qd2 = qrow[2], qd3 = qrow[3];

  float p[WINSZ];
#pragma unroll
  for (int w = 0; w < WINSZ; ++w) p[w] = 0.f;

#pragma unroll
  for (int c = 0; c < 4; ++c) {
    const uint4 qv = (c == 0) ? qd0 : (c == 1) ? qd1 : (c == 2) ? qd2 : qd3;
    const float q0 = bflo(qv.x), q1 = bfhi(qv.x);
    const float q2 = bflo(qv.y), q3 = bfhi(qv.y);
    const float q4 = bflo(qv.z), q5 = bfhi(qv.z);
    const float q6 = bflo(qv.w), q7 = bfhi(qv.w);
#pragma unroll 7
    for (int w = 0; w < WINSZ; ++w) {
      const int r = row + w;
      const uint4 v = Kl[r * 8 + ((half * 4 + c) ^ (r & 7))];
      float a0 = q0 * bflo(v.x);
      float a1 = q1 * bfhi(v.x);
      a0 += q2 * bflo(v.y);
      a1 += q3 * bfhi(v.y);
      a0 += q4 * bflo(v.z);
      a1 += q5 * bfhi(v.z);
      a0 += q6 * bflo(v.w);
      a1 += q7 * bfhi(v.w);
      p[w] += a0 + a1;
    }
  }

#pragma unroll
  for (int w = 0; w < WINSZ; ++w) {
    float t = p[w];
    t += __shfl_xor(t, 1, 64);
    const int pos = n - W2 + w;
    p[w] = (pos < 0 || pos >= Nn) ? -1e30f : t * 0.125f;
  }
  float mx = p[0];
#pragma unroll
  for (int w = 1; w < WINSZ; ++w) mx = fmaxf(mx, p[w]);
  float sum = 0.f;
#pragma unroll
  for (int w = 0; w < WINSZ; ++w) { p[w] = __expf(p[w] - mx); sum += p[w]; }
  const float inv = 1.0f / sum;

  if (n == Nn - 1 && half == 0) {
#pragma unroll
    for (int w = 0; w <= W2; ++w)
      attn_last[(b * Hh + h) * (W2 + 1) + w] = p[w] * inv;
  }

  uint4* orow = (uint4*)(AO + m * Cc + h * Dd) + half * 4;
#pragma unroll
  for (int c = 0; c < 4; ++c) {
    float o0 = 0.f, o1 = 0.f, o2 = 0.f, o3 = 0.f;
    float o4 = 0.f, o5 = 0.f, o6 = 0.f, o7 = 0.f;
#pragma unroll 7
    for (int w = 0; w < WINSZ; ++w) {
      const int r = row + w;
      const uint4 v = Vl[r * 8 + ((half * 4 + c) ^ (r & 7))];
      const float pw = p[w];
      o0 += pw * bflo(v.x);
      o1 += pw * bfhi(v.x);
      o2 += pw * bflo(v.y);
      o3 += pw * bfhi(v.y);
      o4 += pw * bflo(v.z);
      o5 += pw * bfhi(v.z);
      o6 += pw * bflo(v.w);
      o7 += pw * bfhi(v.w);
    }
    unsigned int d0 = (unsigned int)f2bf(o0 * inv) | ((unsigned int)f2bf(o1 * inv) << 16);
    unsigned int d1 = (unsigned int)f2bf(o2 * inv) | ((unsigned int)f2bf(o3 * inv) << 16);
    unsigned int d2 = (unsigned int)f2bf(o4 * inv) | ((unsigned int)f2bf(o5 * inv) << 16);
    unsigned int d3 = (unsigned int)f2bf(o6 * inv) | ((unsigned int)f2bf(o7 * inv) << 16);
    orow[c] = make_uint4(d0, d1, d2, d3);
  }
}

// ---------------- launch ----------------
extern "C" void kernel_launch(void* const* d_in, const int* in_sizes, int n_in,
                              void* d_out, int out_size, void* d_ws, size_t ws_size,
                              hipStream_t stream) {
  const float* q    = (const float*)d_in[0];
  const float* Wq_w = (const float*)d_in[1];
  const float* Wq_b = (const float*)d_in[2];
  const float* Wk_w = (const float*)d_in[3];
  const float* Wk_b = (const float*)d_in[4];
  const float* Wv_w = (const float*)d_in[5];
  const float* Wv_b = (const float*)d_in[6];
  const float* Wo_w = (const float*)d_in[7];
  const float* Wo_b = (const float*)d_in[8];
  float* out = (float*)d_out;                       // [Mm*Cc] + [Bb*Hh*11]
  float* attn_last = out + (size_t)Mm * Cc;

  // workspace carve (bytes)
  char* ws = (char*)d_ws;
  unsigned short* qb   = (unsigned short*)(ws);                       // 16 MB
  unsigned short* Wqkv = (unsigned short*)(ws + 16777216);            // 6 MB
  unsigned short* Wo16 = (unsigned short*)(ws + 16777216 + 6291456);  // 2 MB
  float*          bqkv = (float*)(ws + 25165824);                     // 3072 f32
  unsigned short* QKV  = (unsigned short*)(ws + 25182208);            // 48 MB
  unsigned short* AO   = (unsigned short*)(ws + 75513856);            // 16 MB

  // 1) fused converts (q, Wq, Wk, Wv, Wo) + bias gather — one launch
  cvt_all<<<2048, 256, 0, stream>>>((const float4*)q,
                                    (const float4*)Wq_w, (const float4*)Wk_w,
                                    (const float4*)Wv_w, (const float4*)Wo_w,
                                    Wq_b, Wk_b, Wv_b,
                                    (us4*)qb, (us4*)Wqkv, (us4*)Wo16, bqkv);

  // 2) fused QKV projection: [8192,1024] x [3072,1024]^T -> bf16 [8192,3072]
  {
    dim3 grid((Mm / 128) * (3072 / 128));   // 64*24 = 1536, %8==0, 3 balanced rounds @2/CU
    gemm_22<true><<<grid, 256, 0, stream>>>(qb, Wqkv, bqkv, (void*)QKV, 3072);
  }

  // 3) windowed attention -> bf16 [8192,1024] + attn_last tail of d_out
  {
    dim3 grid(Bb * Hh * (Nn / TN));
    attn_kernel<<<grid, 256, 0, stream>>>(QKV, AO, attn_last);
  }

  // 4) output projection: [8192,1024] x [1024,1024]^T -> fp32 d_out
  {
    dim3 grid((Mm / 128) * (Cc / 128));     // 512, %8==0, exactly all-resident @2/CU
    gemm_22<false><<<grid, 256, 0, stream>>>(AO, Wo16, Wo_b, (void*)out, Cc);
  }
}

// Round 17
// 134.125 us; speedup vs baseline: 1.5857x; 1.0979x over previous
//
#include <hip/hip_runtime.h>
#include <hip/hip_bf16.h>

// Problem constants
#define Bb 2
#define Nn 4096
#define Cc 1024
#define Hh 16
#define Dd 64
#define Mm (Bb*Nn)      // 8192
#define W2 10
#define WINSZ 21        // 2*W2+1

typedef __attribute__((ext_vector_type(8))) short  bf16x8s;
typedef __attribute__((ext_vector_type(4))) float  f32x4;
typedef __attribute__((ext_vector_type(4))) unsigned short us4;

#define AS1 __attribute__((address_space(1)))
#define AS3 __attribute__((address_space(3)))

__device__ __forceinline__ unsigned short f2bf(float f) {
  unsigned int u = __float_as_uint(f);
  u += 0x7FFFu + ((u >> 16) & 1u);
  return (unsigned short)(u >> 16);
}
__device__ __forceinline__ float bflo(unsigned int u) { return __uint_as_float(u << 16); }
__device__ __forceinline__ float bfhi(unsigned int u) { return __uint_as_float(u & 0xFFFF0000u); }

__device__ __forceinline__ us4 cvt4(float4 v) {
  us4 o;
  o.x = f2bf(v.x); o.y = f2bf(v.y); o.z = f2bf(v.z); o.w = f2bf(v.w);
  return o;
}

// ---------------- fused fp32->bf16 converts + bias gather (one launch) ----------------
__global__ __launch_bounds__(256) void cvt_all(const float4* __restrict__ q,
                                               const float4* __restrict__ wq,
                                               const float4* __restrict__ wk,
                                               const float4* __restrict__ wv,
                                               const float4* __restrict__ wo,
                                               const float* __restrict__ bq,
                                               const float* __restrict__ bk,
                                               const float* __restrict__ bv,
                                               us4* __restrict__ qb4,
                                               us4* __restrict__ wqkv4,
                                               us4* __restrict__ wo4,
                                               float* __restrict__ bqkv) {
  const int NQ = 2097152, NW = 262144, TOT = NQ + 4 * NW;
  const int gid = blockIdx.x * 256 + threadIdx.x;
  const int stride = gridDim.x * 256;
  for (int i = gid; i < TOT; i += stride) {
    if (i < NQ) {
      qb4[i] = cvt4(q[i]);
    } else {
      int j = i - NQ;
      int r = j >> 18, k = j & (NW - 1);
      if (r == 0)      wqkv4[k]          = cvt4(wq[k]);
      else if (r == 1) wqkv4[NW + k]     = cvt4(wk[k]);
      else if (r == 2) wqkv4[2 * NW + k] = cvt4(wv[k]);
      else             wo4[k]            = cvt4(wo[k]);
    }
  }
  if (gid < 3072) {
    float v = (gid < 1024) ? bq[gid] : (gid < 2048) ? bk[gid - 1024] : bv[gid - 2048];
    bqkv[gid] = v;
  }
}

// ---------------- 128x256 flight-2 pipelined bf16 NT GEMM (K=1024) — R10-proven ----------------
// 8 waves (2M x 4N, per-wave 64x64), BK=64, THREE LDS buffers; tile t reads buf[t%3]
// while STG(t+2) is issued; end-of-tile counted vmcnt(6) + ONE s_barrier.
// Chunk-XOR swizzle; bijective XCD swizzle + column-major tile walk.
template<bool OUT_BF16>
__global__ __launch_bounds__(512) void gemm_p3(const unsigned short* __restrict__ A,
                                               const unsigned short* __restrict__ Bm,
                                               const float* __restrict__ bias,
                                               void* __restrict__ Cout,
                                               int N) {
  constexpr int K = 1024, NT = 16;
  __shared__ unsigned short lds[3][24576];   // 144 KB

  const int tid = threadIdx.x, wid = tid >> 6, lane = tid & 63;
  const int wm = wid >> 2, wn = wid & 3;

  const int nwg = gridDim.x, cpx = nwg >> 3, bid = blockIdx.x;
  const int swz = (bid & 7) * cpx + (bid >> 3);
  constexpr int NBM = Mm / 128;   // 64
  const int m0 = (swz % NBM) << 7, n0 = (swz / NBM) << 8;

  const int rbase = wid * 8 + (lane >> 3);
  const int cst = ((lane & 7) ^ (lane >> 3)) * 8;
  const unsigned short* aS0 = A + (size_t)(m0 + rbase) * K + cst;
  const unsigned short* aS1 = A + (size_t)(m0 + 64 + rbase) * K + cst;
  const unsigned short* bS0 = Bm + (size_t)(n0 + rbase) * K + cst;
  const unsigned short* bS1 = Bm + (size_t)(n0 + 64 + rbase) * K + cst;
  const unsigned short* bS2 = Bm + (size_t)(n0 + 128 + rbase) * K + cst;
  const unsigned short* bS3 = Bm + (size_t)(n0 + 192 + rbase) * K + cst;
  const int dA0 = wid * 512, dA1 = 4096 + wid * 512;
  const int dB0 = 8192 + wid * 512, dB1 = 12288 + wid * 512;
  const int dB2 = 16384 + wid * 512, dB3 = 20480 + wid * 512;

#define STG(bf, kt) do {                                                                   \
    const size_t ko = (size_t)(kt) * 64;                                                   \
    __builtin_amdgcn_global_load_lds((AS1 const void*)(aS0 + ko), (AS3 void*)(&lds[bf][dA0]), 16, 0, 0); \
    __builtin_amdgcn_global_load_lds((AS1 const void*)(aS1 + ko), (AS3 void*)(&lds[bf][dA1]), 16, 0, 0); \
    __builtin_amdgcn_global_load_lds((AS1 const void*)(bS0 + ko), (AS3 void*)(&lds[bf][dB0]), 16, 0, 0); \
    __builtin_amdgcn_global_load_lds((AS1 const void*)(bS1 + ko), (AS3 void*)(&lds[bf][dB1]), 16, 0, 0); \
    __builtin_amdgcn_global_load_lds((AS1 const void*)(bS2 + ko), (AS3 void*)(&lds[bf][dB2]), 16, 0, 0); \
    __builtin_amdgcn_global_load_lds((AS1 const void*)(bS3 + ko), (AS3 void*)(&lds[bf][dB3]), 16, 0, 0); \
  } while (0)

  int aoff[2][4], boff[2][4];
#pragma unroll
  for (int kk = 0; kk < 2; ++kk) {
    const int chs = ((kk * 4 + (lane >> 4)) ^ (lane & 7)) * 8;
#pragma unroll
    for (int f = 0; f < 4; ++f) {
      aoff[kk][f] = (wm * 64 + f * 16 + (lane & 15)) * 64 + chs;
      boff[kk][f] = 8192 + (wn * 64 + f * 16 + (lane & 15)) * 64 + chs;
    }
  }

  f32x4 acc[4][4] = {};

  STG(0, 0);
  STG(1, 1);
  asm volatile("s_waitcnt vmcnt(6)" ::: "memory");
  __builtin_amdgcn_sched_barrier(0);
  __builtin_amdgcn_s_barrier();
  __builtin_amdgcn_sched_barrier(0);

  int cur = 0, stg = 2;
  for (int t = 0; t < NT; ++t) {
    if (t + 2 < NT) STG(stg, t + 2);

    const unsigned short* L = &lds[cur][0];
    bf16x8s a[2][4], b[2][4];
#pragma unroll
    for (int kk = 0; kk < 2; ++kk) {
#pragma unroll
      for (int f = 0; f < 4; ++f) {
        a[kk][f] = *(const bf16x8s*)(L + aoff[kk][f]);
        b[kk][f] = *(const bf16x8s*)(L + boff[kk][f]);
      }
    }
    __builtin_amdgcn_s_setprio(1);
#pragma unroll
    for (int kk = 0; kk < 2; ++kk)
#pragma unroll
      for (int fm = 0; fm < 4; ++fm)
#pragma unroll
        for (int fn = 0; fn < 4; ++fn)
          acc[fm][fn] = __builtin_amdgcn_mfma_f32_16x16x32_bf16(a[kk][fm], b[kk][fn], acc[fm][fn], 0, 0, 0);
    __builtin_amdgcn_s_setprio(0);

    if (t + 1 < NT) {
      if (t + 2 < NT) asm volatile("s_waitcnt vmcnt(6)" ::: "memory");
      else            asm volatile("s_waitcnt vmcnt(0)" ::: "memory");
      __builtin_amdgcn_sched_barrier(0);
      __builtin_amdgcn_s_barrier();
      __builtin_amdgcn_sched_barrier(0);
    }
    cur = (cur == 2) ? 0 : cur + 1;
    stg = (stg == 2) ? 0 : stg + 1;
  }
#undef STG

  const int r0 = m0 + wm * 64 + (lane >> 4) * 4;
  const int c0 = n0 + wn * 64 + (lane & 15);
#pragma unroll
  for (int fm = 0; fm < 4; ++fm) {
#pragma unroll
    for (int fn = 0; fn < 4; ++fn) {
      const int col = c0 + fn * 16;
      const float bv = bias[col];
#pragma unroll
      for (int r = 0; r < 4; ++r) {
        const int row = r0 + fm * 16 + r;
        const float v = acc[fm][fn][r] + bv;
        if (OUT_BF16)
          ((unsigned short*)Cout)[(size_t)row * N + col] = f2bf(v);
        else
          ((float*)Cout)[(size_t)row * N + col] = v;
      }
    }
  }
}

// ---------------- banded local attention: 4 threads per (b,h,n) row ----------------
// 512 threads = 128 rows per block; each thread owns a d-quarter (16 elems).
// Occupancy: LDS 37.9KB -> 4 blocks/CU, 8 waves/block -> ~24-32 waves/CU (2x prior).
#define TN 128
#define KVROWS (TN + 2 * W2)   // 148 staged rows

__global__ __launch_bounds__(512) void attn_kernel(const unsigned short* __restrict__ QKV, // [Mm][3072]
                                                   unsigned short* __restrict__ AO,        // [Mm][1024]
                                                   float* __restrict__ attn_last) {        // [Bb*Hh*11]
  __shared__ uint4 Kl[KVROWS * 8];
  __shared__ uint4 Vl[KVROWS * 8];

  const int nt = Nn / TN;            // 32
  const int bid = blockIdx.x;
  const int tile = bid & (nt - 1);
  const int bh = bid / nt;
  const int h = bh & (Hh - 1), b = bh / Hh;
  const int n0 = tile * TN;
  const int tid = threadIdx.x;

  // stage K,V rows [n0-10, n0+137], zero-fill OOB, swizzled chunk placement
  for (int idx = tid; idx < KVROWS * 8; idx += 512) {
    const int r = idx >> 3, c = idx & 7;
    const int pos = n0 - W2 + r;
    uint4 kv = make_uint4(0, 0, 0, 0), vv = make_uint4(0, 0, 0, 0);
    if (pos >= 0 && pos < Nn) {
      const uint4* row = (const uint4*)(QKV + (size_t)(b * Nn + pos) * 3072);
      kv = row[128 + h * 8 + c];
      vv = row[256 + h * 8 + c];
    }
    const int slot = c ^ (r & 7);
    Kl[r * 8 + slot] = kv;
    Vl[r * 8 + slot] = vv;
  }
  __syncthreads();

  const int row = tid >> 2;        // 0..127
  const int qtr = tid & 3;         // d-quarter (16 elems = 2 chunks)
  const int n = n0 + row;
  const size_t m = (size_t)b * Nn + n;

  // q quarter-row, packed (2 uint4 = 8 regs)
  const uint4* qrow = (const uint4*)(QKV + m * 3072) + h * 8 + qtr * 2;
  const uint4 qd0 = qrow[0], qd1 = qrow[1];

  float p[WINSZ];
#pragma unroll
  for (int w = 0; w < WINSZ; ++w) p[w] = 0.f;

  // scores: c-outer (2 chunks), w-inner
#pragma unroll
  for (int c = 0; c < 2; ++c) {
    const uint4 qv = (c == 0) ? qd0 : qd1;
    const float q0 = bflo(qv.x), q1 = bfhi(qv.x);
    const float q2 = bflo(qv.y), q3 = bfhi(qv.y);
    const float q4 = bflo(qv.z), q5 = bfhi(qv.z);
    const float q6 = bflo(qv.w), q7 = bfhi(qv.w);
#pragma unroll 7
    for (int w = 0; w < WINSZ; ++w) {
      const int r = row + w;
      const uint4 v = Kl[r * 8 + ((qtr * 2 + c) ^ (r & 7))];
      float a0 = q0 * bflo(v.x);
      float a1 = q1 * bfhi(v.x);
      a0 += q2 * bflo(v.y);
      a1 += q3 * bfhi(v.y);
      a0 += q4 * bflo(v.z);
      a1 += q5 * bfhi(v.z);
      a0 += q6 * bflo(v.w);
      a1 += q7 * bfhi(v.w);
      p[w] += a0 + a1;
    }
  }

  // combine quarters (4-lane group) + scale + mask + softmax
#pragma unroll
  for (int w = 0; w < WINSZ; ++w) {
    float t = p[w];
    t += __shfl_xor(t, 1, 64);
    t += __shfl_xor(t, 2, 64);
    const int pos = n - W2 + w;
    p[w] = (pos < 0 || pos >= Nn) ? -1e30f : t * 0.125f;   // 1/sqrt(64)
  }
  float mx = p[0];
#pragma unroll
  for (int w = 1; w < WINSZ; ++w) mx = fmaxf(mx, p[w]);
  float sum = 0.f;
#pragma unroll
  for (int w = 0; w < WINSZ; ++w) { p[w] = __expf(p[w] - mx); sum += p[w]; }
  const float inv = 1.0f / sum;

  if (n == Nn - 1 && qtr == 0) {
#pragma unroll
    for (int w = 0; w <= W2; ++w)
      attn_last[(b * Hh + h) * (W2 + 1) + w] = p[w] * inv;
  }

  // P·V over this thread's d-quarter (2 chunks of 8), store immediately
  uint4* orow = (uint4*)(AO + m * Cc + h * Dd) + qtr * 2;
#pragma unroll
  for (int c = 0; c < 2; ++c) {
    float o0 = 0.f, o1 = 0.f, o2 = 0.f, o3 = 0.f;
    float o4 = 0.f, o5 = 0.f, o6 = 0.f, o7 = 0.f;
#pragma unroll 7
    for (int w = 0; w < WINSZ; ++w) {
      const int r = row + w;
      const uint4 v = Vl[r * 8 + ((qtr * 2 + c) ^ (r & 7))];
      const float pw = p[w];
      o0 += pw * bflo(v.x);
      o1 += pw * bfhi(v.x);
      o2 += pw * bflo(v.y);
      o3 += pw * bfhi(v.y);
      o4 += pw * bflo(v.z);
      o5 += pw * bfhi(v.z);
      o6 += pw * bflo(v.w);
      o7 += pw * bfhi(v.w);
    }
    unsigned int d0 = (unsigned int)f2bf(o0 * inv) | ((unsigned int)f2bf(o1 * inv) << 16);
    unsigned int d1 = (unsigned int)f2bf(o2 * inv) | ((unsigned int)f2bf(o3 * inv) << 16);
    unsigned int d2 = (unsigned int)f2bf(o4 * inv) | ((unsigned int)f2bf(o5 * inv) << 16);
    unsigned int d3 = (unsigned int)f2bf(o6 * inv) | ((unsigned int)f2bf(o7 * inv) << 16);
    orow[c] = make_uint4(d0, d1, d2, d3);
  }
}

// ---------------- launch ----------------
extern "C" void kernel_launch(void* const* d_in, const int* in_sizes, int n_in,
                              void* d_out, int out_size, void* d_ws, size_t ws_size,
                              hipStream_t stream) {
  const float* q    = (const float*)d_in[0];
  const float* Wq_w = (const float*)d_in[1];
  const float* Wq_b = (const float*)d_in[2];
  const float* Wk_w = (const float*)d_in[3];
  const float* Wk_b = (const float*)d_in[4];
  const float* Wv_w = (const float*)d_in[5];
  const float* Wv_b = (const float*)d_in[6];
  const float* Wo_w = (const float*)d_in[7];
  const float* Wo_b = (const float*)d_in[8];
  float* out = (float*)d_out;                       // [Mm*Cc] + [Bb*Hh*11]
  float* attn_last = out + (size_t)Mm * Cc;

  // workspace carve (bytes)
  char* ws = (char*)d_ws;
  unsigned short* qb   = (unsigned short*)(ws);                       // 16 MB
  unsigned short* Wqkv = (unsigned short*)(ws + 16777216);            // 6 MB
  unsigned short* Wo16 = (unsigned short*)(ws + 16777216 + 6291456);  // 2 MB
  float*          bqkv = (float*)(ws + 25165824);                     // 3072 f32
  unsigned short* QKV  = (unsigned short*)(ws + 25182208);            // 48 MB
  unsigned short* AO   = (unsigned short*)(ws + 75513856);            // 16 MB

  // 1) fused converts (q, Wq, Wk, Wv, Wo) + bias gather — one launch
  cvt_all<<<2048, 256, 0, stream>>>((const float4*)q,
                                    (const float4*)Wq_w, (const float4*)Wk_w,
                                    (const float4*)Wv_w, (const float4*)Wo_w,
                                    Wq_b, Wk_b, Wv_b,
                                    (us4*)qb, (us4*)Wqkv, (us4*)Wo16, bqkv);

  // 2) fused QKV projection: [8192,1024] x [3072,1024]^T -> bf16 [8192,3072]
  {
    dim3 grid((Mm / 128) * (3072 / 256));   // 768, %8==0
    gemm_p3<true><<<grid, 512, 0, stream>>>(qb, Wqkv, bqkv, (void*)QKV, 3072);
  }

  // 3) windowed attention -> bf16 [8192,1024] + attn_last tail of d_out
  {
    dim3 grid(Bb * Hh * (Nn / TN));          // 1024 blocks x 512 thr
    attn_kernel<<<grid, 512, 0, stream>>>(QKV, AO, attn_last);
  }

  // 4) output projection: [8192,1024] x [1024,1024]^T -> fp32 d_out
  {
    dim3 grid((Mm / 128) * (Cc / 256));     // 256, %8==0
    gemm_p3<false><<<grid, 512, 0, stream>>>(AO, Wo16, Wo_b, (void*)out, Cc);
  }
}